// Round 1
// baseline (427.871 us; speedup 1.0000x reference)
//
#include <hip/hip_runtime.h>
#include <hip/hip_bf16.h>
#include <hip/hip_fp16.h>

#define Bn 8
#define Tn 4096
#define En 2048
#define Hn 128

typedef __attribute__((ext_vector_type(8))) short bf16x8;
typedef __attribute__((ext_vector_type(4))) float f32x4;
typedef __attribute__((ext_vector_type(4))) unsigned int u32x4;

static __device__ __forceinline__ unsigned short f2bf(float f) {
    union { float f; unsigned u; } v; v.f = f;
    unsigned r = v.u + 0x7FFFu + ((v.u >> 16) & 1u);
    return (unsigned short)(r >> 16);
}
static __device__ __forceinline__ float h2f(unsigned short bits) {
    __half_raw hr; hr.x = bits;
    return __half2float(__half(hr));
}

// ---------------- K0: transpose+convert weights, fold SCALE*log2e into Wq ----
__global__ __launch_bounds__(256) void prep_w(const float* __restrict__ Wq,
                                              const float* __restrict__ Wk,
                                              const float* __restrict__ Wv,
                                              unsigned short* __restrict__ Wt) {
    int idx = blockIdx.x * 256 + threadIdx.x;          // over 3*E*H, input-coalesced
    int w = idx / (En * Hn);
    int rem = idx - w * (En * Hn);
    int kx = rem >> 7;                                  // k (0..2047)
    int n  = rem & 127;                                 // h (0..127)
    const float* W = (w == 0) ? Wq : (w == 1) ? Wk : Wv;
    float f = W[rem];
    if (w == 0) f *= (0.17677669529663687f * 1.4426950408889634f); // 32^-0.5 * log2(e)
    Wt[(size_t)w * En * Hn + (size_t)n * En + kx] = f2bf(f);
}

// ---------------- K1: q,k,v projections (x fp32 -> bf16 MFMA) ----------------
// grid: (MT/128)*3 ; w = bid%3 selects weight; w==2 writes v TRANSPOSED [b][h][t]
__global__ __launch_bounds__(256) void qkv_gemm(const float* __restrict__ x,
                                                const unsigned short* __restrict__ Wt,
                                                unsigned short* __restrict__ qs,
                                                unsigned short* __restrict__ ks,
                                                unsigned short* __restrict__ vT) {
    __shared__ unsigned short Al[128][88];   // 176B row stride: 16B aligned, 2-way bank max
    __shared__ unsigned short Bl[128][88];
    const int bid = blockIdx.x;
    const int w = bid % 3;
    const int m0 = (bid / 3) * 128;
    const int t = threadIdx.x;
    const int lane = t & 63, wid = t >> 6;
    const int wr = (wid >> 1) * 64, wc = (wid & 1) * 64;
    const int fr = lane & 15, fq = lane >> 4;
    const unsigned short* Wb = Wt + (size_t)w * En * Hn;
    f32x4 acc[4][4] = {};
    for (int k0 = 0; k0 < En; k0 += 64) {
        __syncthreads();
        // A: x[m0..+128][k0..+64] fp32 -> bf16 LDS
        #pragma unroll
        for (int it = 0; it < 8; ++it) {
            int idx = it * 256 + t;
            int row = idx >> 4, ch = idx & 15;
            float4 v4 = *reinterpret_cast<const float4*>(&x[(size_t)(m0 + row) * En + k0 + ch * 4]);
            ushort4 o;
            o.x = f2bf(v4.x); o.y = f2bf(v4.y); o.z = f2bf(v4.z); o.w = f2bf(v4.w);
            *reinterpret_cast<ushort4*>(&Al[row][ch * 4]) = o;
        }
        // B: Wt[w][n][k0..+64] bf16 (already transposed)
        #pragma unroll
        for (int it = 0; it < 4; ++it) {
            int idx = it * 256 + t;
            int row = idx >> 3, ch = idx & 7;
            *reinterpret_cast<u32x4*>(&Bl[row][ch * 8]) =
                *reinterpret_cast<const u32x4*>(&Wb[(size_t)row * En + k0 + ch * 8]);
        }
        __syncthreads();
        #pragma unroll
        for (int ksub = 0; ksub < 2; ++ksub) {
            bf16x8 av[4], bv[4];
            #pragma unroll
            for (int mi = 0; mi < 4; ++mi)
                av[mi] = *reinterpret_cast<const bf16x8*>(&Al[wr + mi * 16 + fr][ksub * 32 + fq * 8]);
            #pragma unroll
            for (int ni = 0; ni < 4; ++ni)
                bv[ni] = *reinterpret_cast<const bf16x8*>(&Bl[wc + ni * 16 + fr][ksub * 32 + fq * 8]);
            #pragma unroll
            for (int mi = 0; mi < 4; ++mi)
                #pragma unroll
                for (int ni = 0; ni < 4; ++ni)
                    acc[mi][ni] = __builtin_amdgcn_mfma_f32_16x16x32_bf16(av[mi], bv[ni], acc[mi][ni], 0, 0, 0);
        }
    }
    if (w < 2) {
        unsigned short* out = (w == 0) ? qs : ks;
        #pragma unroll
        for (int mi = 0; mi < 4; ++mi)
            #pragma unroll
            for (int ni = 0; ni < 4; ++ni)
                #pragma unroll
                for (int r = 0; r < 4; ++r) {
                    int row = m0 + wr + mi * 16 + fq * 4 + r;
                    int col = wc + ni * 16 + fr;
                    out[(size_t)row * Hn + col] = f2bf(acc[mi][ni][r]);
                }
    } else {
        int b = m0 / Tn;
        int tb = m0 - b * Tn;
        #pragma unroll
        for (int mi = 0; mi < 4; ++mi)
            #pragma unroll
            for (int ni = 0; ni < 4; ++ni)
                #pragma unroll
                for (int r = 0; r < 4; ++r) {
                    int tt = tb + wr + mi * 16 + fq * 4 + r;
                    int h  = wc + ni * 16 + fr;
                    vT[((size_t)b * Hn + h) * Tn + tt] = f2bf(acc[mi][ni][r]);
                }
    }
}

// ---------------- K2: S' = (q*SCALE*log2e) . k^T  -> fp16 [b][q][k] ----------
__global__ __launch_bounds__(256) void s_gemm(const unsigned short* __restrict__ qs,
                                              const unsigned short* __restrict__ ks,
                                              __half* __restrict__ S) {
    __shared__ unsigned short Ql[128][88];
    __shared__ unsigned short Kl[128][88];
    const int bid = blockIdx.x;
    const int b = bid >> 10;
    const int rem = bid & 1023;
    const int m0 = (rem >> 5) << 7;     // q tile
    const int n0 = (rem & 31) << 7;     // key tile (fastest -> k panel L2 reuse)
    const unsigned short* qb = qs + (size_t)b * Tn * Hn;
    const unsigned short* kb = ks + (size_t)b * Tn * Hn;
    const int t = threadIdx.x;
    const int lane = t & 63, wid = t >> 6;
    const int wr = (wid >> 1) * 64, wc = (wid & 1) * 64;
    const int fr = lane & 15, fq = lane >> 4;
    f32x4 acc[4][4] = {};
    #pragma unroll
    for (int kh = 0; kh < 2; ++kh) {
        __syncthreads();
        #pragma unroll
        for (int it = 0; it < 4; ++it) {
            int idx = it * 256 + t;
            int row = idx >> 3, ch = idx & 7;
            *reinterpret_cast<u32x4*>(&Ql[row][ch * 8]) =
                *reinterpret_cast<const u32x4*>(&qb[(size_t)(m0 + row) * Hn + kh * 64 + ch * 8]);
            *reinterpret_cast<u32x4*>(&Kl[row][ch * 8]) =
                *reinterpret_cast<const u32x4*>(&kb[(size_t)(n0 + row) * Hn + kh * 64 + ch * 8]);
        }
        __syncthreads();
        #pragma unroll
        for (int ksub = 0; ksub < 2; ++ksub) {
            bf16x8 av[4], bv[4];
            #pragma unroll
            for (int mi = 0; mi < 4; ++mi)
                av[mi] = *reinterpret_cast<const bf16x8*>(&Ql[wr + mi * 16 + fr][ksub * 32 + fq * 8]);
            #pragma unroll
            for (int ni = 0; ni < 4; ++ni)
                bv[ni] = *reinterpret_cast<const bf16x8*>(&Kl[wc + ni * 16 + fr][ksub * 32 + fq * 8]);
            #pragma unroll
            for (int mi = 0; mi < 4; ++mi)
                #pragma unroll
                for (int ni = 0; ni < 4; ++ni)
                    acc[mi][ni] = __builtin_amdgcn_mfma_f32_16x16x32_bf16(av[mi], bv[ni], acc[mi][ni], 0, 0, 0);
        }
    }
    __half* Sb = S + (size_t)b * Tn * Tn;
    #pragma unroll
    for (int mi = 0; mi < 4; ++mi)
        #pragma unroll
        for (int ni = 0; ni < 4; ++ni)
            #pragma unroll
            for (int r = 0; r < 4; ++r) {
                int row = m0 + wr + mi * 16 + fq * 4 + r;
                int col = n0 + wc + ni * 16 + fr;
                Sb[(size_t)row * Tn + col] = __float2half(acc[mi][ni][r]);
            }
}

// ---------------- K3a: per-column (over q) online max/sumexp partials --------
// softmax is over axis=1 (query) -> reduce DOWN the rows of S'[q][k]
__global__ __launch_bounds__(256) void stats_part(const __half* __restrict__ S,
                                                  float2* __restrict__ part) {
    const int bid = blockIdx.x;     // 8 batches * 4 colblocks * 8 rowsplits = 256
    const int b = bid >> 5;
    const int rem = bid & 31;
    const int cb = rem & 3;
    const int rs = rem >> 2;
    const int t = threadIdx.x;
    const int c0 = cb * 1024 + t * 4;
    const __half* Sb = S + (size_t)b * Tn * Tn;
    float m[4] = {-INFINITY, -INFINITY, -INFINITY, -INFINITY};
    float l[4] = {0.f, 0.f, 0.f, 0.f};
    #pragma unroll 8
    for (int i = 0; i < 512; ++i) {
        int qrow = rs * 512 + i;
        uint2 raw = *reinterpret_cast<const uint2*>(&Sb[(size_t)qrow * Tn + c0]);
        float s[4];
        s[0] = h2f((unsigned short)(raw.x & 0xffff));
        s[1] = h2f((unsigned short)(raw.x >> 16));
        s[2] = h2f((unsigned short)(raw.y & 0xffff));
        s[3] = h2f((unsigned short)(raw.y >> 16));
        #pragma unroll
        for (int j = 0; j < 4; ++j) {
            float mn = fmaxf(m[j], s[j]);
            l[j] = l[j] * __builtin_amdgcn_exp2f(m[j] - mn) + __builtin_amdgcn_exp2f(s[j] - mn);
            m[j] = mn;
        }
    }
    #pragma unroll
    for (int j = 0; j < 4; ++j)
        part[((size_t)(b * Tn + c0 + j)) * 8 + rs] = make_float2(m[j], l[j]);
}

// ---------------- K3b: combine 8 partials -> stats[b][k] = (m, 1/l) ----------
__global__ __launch_bounds__(256) void stats_comb(const float2* __restrict__ part,
                                                  float2* __restrict__ stats) {
    int g = blockIdx.x * 256 + threadIdx.x;   // 8*4096
    float M = -INFINITY;
    float2 p[8];
    #pragma unroll
    for (int i = 0; i < 8; ++i) { p[i] = part[(size_t)g * 8 + i]; M = fmaxf(M, p[i].x); }
    float L = 0.f;
    #pragma unroll
    for (int i = 0; i < 8; ++i) L += p[i].y * __builtin_amdgcn_exp2f(p[i].x - M);
    stats[g] = make_float2(M, 1.0f / L);
}

// ---------------- K4: out[b][q][h] = sum_k exp2(S'-m_k)*r_k * v[k][h] --------
// grid: 8 * (4096/64); BM=64, BN=128, BK=64
__global__ __launch_bounds__(256) void pv_gemm(const __half* __restrict__ S,
                                               const float2* __restrict__ stats,
                                               const unsigned short* __restrict__ vT,
                                               float* __restrict__ out) {
    __shared__ unsigned short Pl[64][88];
    __shared__ unsigned short Vl[128][88];
    const int bid = blockIdx.x;
    const int b = bid >> 6;
    const int q0 = (bid & 63) * 64;
    const int t = threadIdx.x;
    const int lane = t & 63, wid = t >> 6;
    const int wr = (wid & 1) * 32, wc = (wid >> 1) * 64;
    const int fr = lane & 15, fq = lane >> 4;
    const __half* Sb = S + (size_t)b * Tn * Tn;
    const unsigned short* Vb = vT + (size_t)b * Hn * Tn;
    const float2* stb = stats + b * Tn;
    const int prow = t >> 3;   // 0..31
    const int pch = t & 7;     // fixed 16B chunk within 64-col panel
    f32x4 acc[2][4] = {};
    for (int kt = 0; kt < 64; ++kt) {
        __syncthreads();
        // stats for my 8 columns (L1/L2 resident: 32KB per batch)
        const float4* stq = reinterpret_cast<const float4*>(stb + kt * 64 + pch * 8);
        float4 s0 = stq[0], s1 = stq[1], s2 = stq[2], s3 = stq[3];
        float m2[8] = {s0.x, s0.z, s1.x, s1.z, s2.x, s2.z, s3.x, s3.z};
        float rr[8] = {s0.y, s0.w, s1.y, s1.w, s2.y, s2.w, s3.y, s3.w};
        // P tile: fp16 S' -> exp2(s - m)*r -> bf16
        #pragma unroll
        for (int it = 0; it < 2; ++it) {
            int row = it * 32 + prow;
            u32x4 raw = *reinterpret_cast<const u32x4*>(&Sb[(size_t)(q0 + row) * Tn + kt * 64 + pch * 8]);
            unsigned pk[4];
            #pragma unroll
            for (int i = 0; i < 4; ++i) {
                float f0 = h2f((unsigned short)(raw[i] & 0xffff));
                float f1 = h2f((unsigned short)(raw[i] >> 16));
                float p0 = __builtin_amdgcn_exp2f(f0 - m2[2 * i]) * rr[2 * i];
                float p1 = __builtin_amdgcn_exp2f(f1 - m2[2 * i + 1]) * rr[2 * i + 1];
                pk[i] = (unsigned)f2bf(p0) | ((unsigned)f2bf(p1) << 16);
            }
            *reinterpret_cast<u32x4*>(&Pl[row][pch * 8]) = *reinterpret_cast<u32x4*>(pk);
        }
        // V tile (vT is [h][t]: linear rows)
        #pragma unroll
        for (int it = 0; it < 4; ++it) {
            int row = it * 32 + prow;
            *reinterpret_cast<u32x4*>(&Vl[row][pch * 8]) =
                *reinterpret_cast<const u32x4*>(&Vb[(size_t)row * Tn + kt * 64 + pch * 8]);
        }
        __syncthreads();
        #pragma unroll
        for (int ksub = 0; ksub < 2; ++ksub) {
            bf16x8 av[2], bv[4];
            #pragma unroll
            for (int mi = 0; mi < 2; ++mi)
                av[mi] = *reinterpret_cast<const bf16x8*>(&Pl[wr + mi * 16 + fr][ksub * 32 + fq * 8]);
            #pragma unroll
            for (int ni = 0; ni < 4; ++ni)
                bv[ni] = *reinterpret_cast<const bf16x8*>(&Vl[wc + ni * 16 + fr][ksub * 32 + fq * 8]);
            #pragma unroll
            for (int mi = 0; mi < 2; ++mi)
                #pragma unroll
                for (int ni = 0; ni < 4; ++ni)
                    acc[mi][ni] = __builtin_amdgcn_mfma_f32_16x16x32_bf16(av[mi], bv[ni], acc[mi][ni], 0, 0, 0);
        }
    }
    #pragma unroll
    for (int mi = 0; mi < 2; ++mi)
        #pragma unroll
        for (int ni = 0; ni < 4; ++ni)
            #pragma unroll
            for (int r = 0; r < 4; ++r) {
                int row = q0 + wr + mi * 16 + fq * 4 + r;
                int col = wc + ni * 16 + fr;
                out[((size_t)b * Tn + row) * Hn + col] = acc[mi][ni][r];
            }
}

extern "C" void kernel_launch(void* const* d_in, const int* in_sizes, int n_in,
                              void* d_out, int out_size, void* d_ws, size_t ws_size,
                              hipStream_t stream) {
    const float* x  = (const float*)d_in[0];
    const float* Wq = (const float*)d_in[1];
    const float* Wk = (const float*)d_in[2];
    const float* Wv = (const float*)d_in[3];
    float* out = (float*)d_out;

    char* p = (char*)d_ws;
    unsigned short* qs = (unsigned short*)p; p += (size_t)Bn * Tn * Hn * 2;
    unsigned short* ks = (unsigned short*)p; p += (size_t)Bn * Tn * Hn * 2;
    unsigned short* vT = (unsigned short*)p; p += (size_t)Bn * Tn * Hn * 2;
    unsigned short* Wt = (unsigned short*)p; p += (size_t)3 * En * Hn * 2;
    __half* S          = (__half*)p;         p += (size_t)Bn * Tn * Tn * 2;
    float2* part       = (float2*)p;         p += (size_t)Bn * Tn * 8 * sizeof(float2);
    float2* stats      = (float2*)p;         p += (size_t)Bn * Tn * sizeof(float2);
    size_t needed = (size_t)(p - (char*)d_ws);
    if (ws_size < needed) return;  // workspace too small: leave output poisoned as a clear signal

    prep_w<<<dim3(3 * En * Hn / 256), dim3(256), 0, stream>>>(Wq, Wk, Wv, Wt);
    qkv_gemm<<<dim3((Bn * Tn / 128) * 3), dim3(256), 0, stream>>>(x, Wt, qs, ks, vT);
    s_gemm<<<dim3(Bn * (Tn / 128) * (Tn / 128)), dim3(256), 0, stream>>>(qs, ks, S);
    stats_part<<<dim3(Bn * 32), dim3(256), 0, stream>>>(S, part);
    stats_comb<<<dim3(Bn * Tn / 256), dim3(256), 0, stream>>>(part, stats);
    pv_gemm<<<dim3(Bn * (Tn / 64)), dim3(256), 0, stream>>>(S, stats, vT, out);
}

// Round 2
// 346.447 us; speedup vs baseline: 1.2350x; 1.2350x over previous
//
#include <hip/hip_runtime.h>
#include <hip/hip_bf16.h>
#include <hip/hip_fp16.h>

#define Bn 8
#define Tn 4096
#define En 2048
#define Hn 128

typedef __attribute__((ext_vector_type(8))) short bf16x8;
typedef __attribute__((ext_vector_type(4))) float f32x4;
typedef __attribute__((ext_vector_type(4))) unsigned int u32x4;

static __device__ __forceinline__ unsigned short f2bf(float f) {
    union { float f; unsigned u; } v; v.f = f;
    unsigned r = v.u + 0x7FFFu + ((v.u >> 16) & 1u);
    return (unsigned short)(r >> 16);
}
static __device__ __forceinline__ float h2f(unsigned short bits) {
    __half_raw hr; hr.x = bits;
    return __half2float(__half(hr));
}

// ---------------- K0: transpose+convert weights, fold SCALE*log2e into Wq ----
__global__ __launch_bounds__(256) void prep_w(const float* __restrict__ Wq,
                                              const float* __restrict__ Wk,
                                              const float* __restrict__ Wv,
                                              unsigned short* __restrict__ Wt) {
    int idx = blockIdx.x * 256 + threadIdx.x;          // over 3*E*H, input-coalesced
    int w = idx / (En * Hn);
    int rem = idx - w * (En * Hn);
    int kx = rem >> 7;                                  // k (0..2047)
    int n  = rem & 127;                                 // h (0..127)
    const float* W = (w == 0) ? Wq : (w == 1) ? Wk : Wv;
    float f = W[rem];
    if (w == 0) f *= (0.17677669529663687f * 1.4426950408889634f); // 32^-0.5 * log2(e)
    Wt[(size_t)w * En * Hn + (size_t)n * En + kx] = f2bf(f);
}

// ---------------- K1: FUSED q,k,v projection: stage x once, 3 weight panels --
// grid: 32768/64 = 512 blocks, 512 threads (8 waves = 2M x 4N over 64x384)
__global__ __launch_bounds__(512) void qkv_fused(const float* __restrict__ x,
                                                 const unsigned short* __restrict__ Wt,
                                                 unsigned short* __restrict__ qs,
                                                 unsigned short* __restrict__ ks,
                                                 unsigned short* __restrict__ vT) {
    __shared__ unsigned short Al[64][72];    // 144B row stride: 16B-aligned, balanced banks
    __shared__ unsigned short Bl[384][72];   // all three weight panels [3*128][64]
    const int m0 = blockIdx.x * 64;
    const int b = m0 / Tn;
    const int tb = m0 - b * Tn;
    const int t = threadIdx.x;
    const int lane = t & 63, wid = t >> 6;
    const int wm = wid >> 2, wn = wid & 3;   // 2 x 4 wave grid
    const int fr = lane & 15, fq = lane >> 4;
    f32x4 acc[2][6] = {};
    for (int k0 = 0; k0 < En; k0 += 64) {
        __syncthreads();
        // A: x[m0..+64][k0..+64] fp32 -> bf16 LDS (staged ONCE for all 3 panels)
        #pragma unroll
        for (int it = 0; it < 2; ++it) {
            int idx = it * 512 + t;
            int row = idx >> 4, ch = idx & 15;
            float4 v4 = *reinterpret_cast<const float4*>(&x[(size_t)(m0 + row) * En + k0 + ch * 4]);
            ushort4 o;
            o.x = f2bf(v4.x); o.y = f2bf(v4.y); o.z = f2bf(v4.z); o.w = f2bf(v4.w);
            *reinterpret_cast<ushort4*>(&Al[row][ch * 4]) = o;
        }
        // B: Wt[0..2][n][k0..+64] bf16 (1.5MB total -> L2-resident)
        #pragma unroll
        for (int it = 0; it < 6; ++it) {
            int idx = it * 512 + t;
            int row = idx >> 3, ch = idx & 7;
            *reinterpret_cast<u32x4*>(&Bl[row][ch * 8]) =
                *reinterpret_cast<const u32x4*>(&Wt[(size_t)row * En + k0 + ch * 8]);
        }
        __syncthreads();
        #pragma unroll
        for (int ksub = 0; ksub < 2; ++ksub) {
            bf16x8 av[2], bv[6];
            #pragma unroll
            for (int mi = 0; mi < 2; ++mi)
                av[mi] = *reinterpret_cast<const bf16x8*>(&Al[wm * 32 + mi * 16 + fr][ksub * 32 + fq * 8]);
            #pragma unroll
            for (int ni = 0; ni < 6; ++ni)
                bv[ni] = *reinterpret_cast<const bf16x8*>(&Bl[wn * 96 + ni * 16 + fr][ksub * 32 + fq * 8]);
            #pragma unroll
            for (int mi = 0; mi < 2; ++mi)
                #pragma unroll
                for (int ni = 0; ni < 6; ++ni)
                    acc[mi][ni] = __builtin_amdgcn_mfma_f32_16x16x32_bf16(av[mi], bv[ni], acc[mi][ni], 0, 0, 0);
        }
    }
    #pragma unroll
    for (int mi = 0; mi < 2; ++mi)
        #pragma unroll
        for (int ni = 0; ni < 6; ++ni) {
            int c = wn * 96 + ni * 16 + fr;   // 0..383: [q | k | v]
            int w = c >> 7, h = c & 127;
            #pragma unroll
            for (int r = 0; r < 4; ++r) {
                int rloc = wm * 32 + mi * 16 + fq * 4 + r;
                unsigned short val = f2bf(acc[mi][ni][r]);
                if (w == 0)      qs[(size_t)(m0 + rloc) * Hn + h] = val;
                else if (w == 1) ks[(size_t)(m0 + rloc) * Hn + h] = val;
                else             vT[((size_t)b * Hn + h) * Tn + tb + rloc] = val;
            }
        }
}

// ---------------- K2: S' = q'.k^T -> fp16 [b][q][k]  +  fused column stats ---
// softmax is over axis=1 (query): per-column (key) max/sumexp partial per tile
__global__ __launch_bounds__(256) void s_gemm(const unsigned short* __restrict__ qs,
                                              const unsigned short* __restrict__ ks,
                                              __half* __restrict__ S,
                                              float2* __restrict__ part) {
    __shared__ unsigned short Ql[128][88];
    __shared__ unsigned short Kl[128][88];
    __shared__ float2 sPart[4][128];
    const int bid = blockIdx.x;
    const int b = bid >> 10;
    const int rem = bid & 1023;
    const int mt = rem >> 5;            // q tile index (0..31)
    const int m0 = mt << 7;
    const int n0 = (rem & 31) << 7;     // key tile (fastest -> k panel L2 reuse)
    const unsigned short* qb = qs + (size_t)b * Tn * Hn;
    const unsigned short* kb = ks + (size_t)b * Tn * Hn;
    const int t = threadIdx.x;
    const int lane = t & 63, wid = t >> 6;
    const int wr = (wid >> 1) * 64, wc = (wid & 1) * 64;
    const int fr = lane & 15, fq = lane >> 4;
    f32x4 acc[4][4] = {};
    #pragma unroll
    for (int kh = 0; kh < 2; ++kh) {
        __syncthreads();
        #pragma unroll
        for (int it = 0; it < 4; ++it) {
            int idx = it * 256 + t;
            int row = idx >> 3, ch = idx & 7;
            *reinterpret_cast<u32x4*>(&Ql[row][ch * 8]) =
                *reinterpret_cast<const u32x4*>(&qb[(size_t)(m0 + row) * Hn + kh * 64 + ch * 8]);
            *reinterpret_cast<u32x4*>(&Kl[row][ch * 8]) =
                *reinterpret_cast<const u32x4*>(&kb[(size_t)(n0 + row) * Hn + kh * 64 + ch * 8]);
        }
        __syncthreads();
        #pragma unroll
        for (int ksub = 0; ksub < 2; ++ksub) {
            bf16x8 av[4], bv[4];
            #pragma unroll
            for (int mi = 0; mi < 4; ++mi)
                av[mi] = *reinterpret_cast<const bf16x8*>(&Ql[wr + mi * 16 + fr][ksub * 32 + fq * 8]);
            #pragma unroll
            for (int ni = 0; ni < 4; ++ni)
                bv[ni] = *reinterpret_cast<const bf16x8*>(&Kl[wc + ni * 16 + fr][ksub * 32 + fq * 8]);
            #pragma unroll
            for (int mi = 0; mi < 4; ++mi)
                #pragma unroll
                for (int ni = 0; ni < 4; ++ni)
                    acc[mi][ni] = __builtin_amdgcn_mfma_f32_16x16x32_bf16(av[mi], bv[ni], acc[mi][ni], 0, 0, 0);
        }
    }
    // write S tile
    __half* Sb = S + (size_t)b * Tn * Tn;
    #pragma unroll
    for (int mi = 0; mi < 4; ++mi)
        #pragma unroll
        for (int ni = 0; ni < 4; ++ni)
            #pragma unroll
            for (int r = 0; r < 4; ++r) {
                int row = m0 + wr + mi * 16 + fq * 4 + r;
                int col = n0 + wc + ni * 16 + fr;
                Sb[(size_t)row * Tn + col] = __float2half(acc[mi][ni][r]);
            }
    // fused per-column (over q) stats: in-lane 16 vals -> shfl over fq -> LDS over waves
    #pragma unroll
    for (int ni = 0; ni < 4; ++ni) {
        float mm = -INFINITY;
        #pragma unroll
        for (int mi = 0; mi < 4; ++mi)
            #pragma unroll
            for (int r = 0; r < 4; ++r)
                mm = fmaxf(mm, acc[mi][ni][r]);
        float ll = 0.f;
        #pragma unroll
        for (int mi = 0; mi < 4; ++mi)
            #pragma unroll
            for (int r = 0; r < 4; ++r)
                ll += __builtin_amdgcn_exp2f(acc[mi][ni][r] - mm);
        #pragma unroll
        for (int off = 16; off <= 32; off <<= 1) {
            float mo = __shfl_xor(mm, off);
            float lo = __shfl_xor(ll, off);
            float mn = fmaxf(mm, mo);
            ll = ll * __builtin_amdgcn_exp2f(mm - mn) + lo * __builtin_amdgcn_exp2f(mo - mn);
            mm = mn;
        }
        if (fq == 0) sPart[wid][wc + ni * 16 + fr] = make_float2(mm, ll);
    }
    __syncthreads();
    if (t < 128) {
        int col = t;
        int w = col >> 6;                      // waves (0,2) own cols 0-63; (1,3) own 64-127
        float2 a = sPart[w][col];
        float2 c2 = sPart[w + 2][col];
        float mn = fmaxf(a.x, c2.x);
        float L = a.y * __builtin_amdgcn_exp2f(a.x - mn) + c2.y * __builtin_amdgcn_exp2f(c2.x - mn);
        part[((size_t)b * Tn + n0 + col) * 32 + mt] = make_float2(mn, L);
    }
}

// ---------------- K3: combine 32 tile-partials -> stats[b][k] = (m, 1/l) -----
__global__ __launch_bounds__(256) void stats_comb(const float2* __restrict__ part,
                                                  float2* __restrict__ stats) {
    int g = blockIdx.x * 256 + threadIdx.x;   // 8*4096
    const float2* pp = part + (size_t)g * 32;
    float M = -INFINITY;
    #pragma unroll
    for (int i = 0; i < 32; ++i) M = fmaxf(M, pp[i].x);
    float L = 0.f;
    #pragma unroll
    for (int i = 0; i < 32; ++i) L += pp[i].y * __builtin_amdgcn_exp2f(pp[i].x - M);
    stats[g] = make_float2(M, 1.0f / L);
}

// ---------------- K4: out[b][q][h] = sum_k exp2(S'-m_k)*r_k * v[k][h] --------
// grid: 8 * (4096/64); BM=64, BN=128, BK=64
__global__ __launch_bounds__(256) void pv_gemm(const __half* __restrict__ S,
                                               const float2* __restrict__ stats,
                                               const unsigned short* __restrict__ vT,
                                               float* __restrict__ out) {
    __shared__ unsigned short Pl[64][88];
    __shared__ unsigned short Vl[128][88];
    const int bid = blockIdx.x;
    const int b = bid >> 6;
    const int q0 = (bid & 63) * 64;
    const int t = threadIdx.x;
    const int lane = t & 63, wid = t >> 6;
    const int wr = (wid & 1) * 32, wc = (wid >> 1) * 64;
    const int fr = lane & 15, fq = lane >> 4;
    const __half* Sb = S + (size_t)b * Tn * Tn;
    const unsigned short* Vb = vT + (size_t)b * Hn * Tn;
    const float2* stb = stats + b * Tn;
    const int prow = t >> 3;   // 0..31
    const int pch = t & 7;     // fixed 16B chunk within 64-col panel
    f32x4 acc[2][4] = {};
    for (int kt = 0; kt < 64; ++kt) {
        __syncthreads();
        // stats for my 8 columns (L2 resident: 32KB per batch)
        const float4* stq = reinterpret_cast<const float4*>(stb + kt * 64 + pch * 8);
        float4 s0 = stq[0], s1 = stq[1], s2 = stq[2], s3 = stq[3];
        float m2[8] = {s0.x, s0.z, s1.x, s1.z, s2.x, s2.z, s3.x, s3.z};
        float rr[8] = {s0.y, s0.w, s1.y, s1.w, s2.y, s2.w, s3.y, s3.w};
        // P tile: fp16 S' -> exp2(s - m)*r -> bf16
        #pragma unroll
        for (int it = 0; it < 2; ++it) {
            int row = it * 32 + prow;
            u32x4 raw = *reinterpret_cast<const u32x4*>(&Sb[(size_t)(q0 + row) * Tn + kt * 64 + pch * 8]);
            unsigned pk[4];
            #pragma unroll
            for (int i = 0; i < 4; ++i) {
                float f0 = h2f((unsigned short)(raw[i] & 0xffff));
                float f1 = h2f((unsigned short)(raw[i] >> 16));
                float p0 = __builtin_amdgcn_exp2f(f0 - m2[2 * i]) * rr[2 * i];
                float p1 = __builtin_amdgcn_exp2f(f1 - m2[2 * i + 1]) * rr[2 * i + 1];
                pk[i] = (unsigned)f2bf(p0) | ((unsigned)f2bf(p1) << 16);
            }
            *reinterpret_cast<u32x4*>(&Pl[row][pch * 8]) = *reinterpret_cast<u32x4*>(pk);
        }
        // V tile (vT is [h][t]: linear rows)
        #pragma unroll
        for (int it = 0; it < 4; ++it) {
            int row = it * 32 + prow;
            *reinterpret_cast<u32x4*>(&Vl[row][pch * 8]) =
                *reinterpret_cast<const u32x4*>(&Vb[(size_t)row * Tn + kt * 64 + pch * 8]);
        }
        __syncthreads();
        #pragma unroll
        for (int ksub = 0; ksub < 2; ++ksub) {
            bf16x8 av[2], bv[4];
            #pragma unroll
            for (int mi = 0; mi < 2; ++mi)
                av[mi] = *reinterpret_cast<const bf16x8*>(&Pl[wr + mi * 16 + fr][ksub * 32 + fq * 8]);
            #pragma unroll
            for (int ni = 0; ni < 4; ++ni)
                bv[ni] = *reinterpret_cast<const bf16x8*>(&Vl[wc + ni * 16 + fr][ksub * 32 + fq * 8]);
            #pragma unroll
            for (int mi = 0; mi < 2; ++mi)
                #pragma unroll
                for (int ni = 0; ni < 4; ++ni)
                    acc[mi][ni] = __builtin_amdgcn_mfma_f32_16x16x32_bf16(av[mi], bv[ni], acc[mi][ni], 0, 0, 0);
        }
    }
    #pragma unroll
    for (int mi = 0; mi < 2; ++mi)
        #pragma unroll
        for (int ni = 0; ni < 4; ++ni)
            #pragma unroll
            for (int r = 0; r < 4; ++r) {
                int row = q0 + wr + mi * 16 + fq * 4 + r;
                int col = wc + ni * 16 + fr;
                out[((size_t)b * Tn + row) * Hn + col] = acc[mi][ni][r];
            }
}

extern "C" void kernel_launch(void* const* d_in, const int* in_sizes, int n_in,
                              void* d_out, int out_size, void* d_ws, size_t ws_size,
                              hipStream_t stream) {
    const float* x  = (const float*)d_in[0];
    const float* Wq = (const float*)d_in[1];
    const float* Wk = (const float*)d_in[2];
    const float* Wv = (const float*)d_in[3];
    float* out = (float*)d_out;

    char* p = (char*)d_ws;
    unsigned short* qs = (unsigned short*)p; p += (size_t)Bn * Tn * Hn * 2;
    unsigned short* ks = (unsigned short*)p; p += (size_t)Bn * Tn * Hn * 2;
    unsigned short* vT = (unsigned short*)p; p += (size_t)Bn * Tn * Hn * 2;
    unsigned short* Wt = (unsigned short*)p; p += (size_t)3 * En * Hn * 2;
    __half* S          = (__half*)p;         p += (size_t)Bn * Tn * Tn * 2;
    float2* part       = (float2*)p;         p += (size_t)Bn * Tn * 32 * sizeof(float2);
    float2* stats      = (float2*)p;         p += (size_t)Bn * Tn * sizeof(float2);
    size_t needed = (size_t)(p - (char*)d_ws);
    if (ws_size < needed) return;  // workspace too small: leave output poisoned as a clear signal

    prep_w<<<dim3(3 * En * Hn / 256), dim3(256), 0, stream>>>(Wq, Wk, Wv, Wt);
    qkv_fused<<<dim3(Bn * Tn / 64), dim3(512), 0, stream>>>(x, Wt, qs, ks, vT);
    s_gemm<<<dim3(Bn * (Tn / 128) * (Tn / 128)), dim3(256), 0, stream>>>(qs, ks, S, part);
    stats_comb<<<dim3(Bn * Tn / 256), dim3(256), 0, stream>>>(part, stats);
    pv_gemm<<<dim3(Bn * (Tn / 64)), dim3(256), 0, stream>>>(S, stats, vT, out);
}

// Round 3
// 336.436 us; speedup vs baseline: 1.2718x; 1.0298x over previous
//
#include <hip/hip_runtime.h>
#include <hip/hip_bf16.h>
#include <hip/hip_fp16.h>

#define Bn 8
#define Tn 4096
#define En 2048
#define Hn 128

typedef __attribute__((ext_vector_type(8))) short bf16x8;
typedef __attribute__((ext_vector_type(4))) float f32x4;
typedef __attribute__((ext_vector_type(4))) unsigned int u32x4;

static __device__ __forceinline__ unsigned short f2bf(float f) {
    union { float f; unsigned u; } v; v.f = f;
    unsigned r = v.u + 0x7FFFu + ((v.u >> 16) & 1u);
    return (unsigned short)(r >> 16);
}
static __device__ __forceinline__ float h2f(unsigned short bits) {
    __half_raw hr; hr.x = bits;
    return __half2float(__half(hr));
}

// ---------------- K0: transpose+convert weights, fold SCALE*log2e into Wq ----
__global__ __launch_bounds__(256) void prep_w(const float* __restrict__ Wq,
                                              const float* __restrict__ Wk,
                                              const float* __restrict__ Wv,
                                              unsigned short* __restrict__ Wt) {
    int idx = blockIdx.x * 256 + threadIdx.x;          // over 3*E*H, input-coalesced
    int w = idx / (En * Hn);
    int rem = idx - w * (En * Hn);
    int kx = rem >> 7;                                  // k (0..2047)
    int n  = rem & 127;                                 // h (0..127)
    const float* W = (w == 0) ? Wq : (w == 1) ? Wk : Wv;
    float f = W[rem];
    if (w == 0) f *= (0.17677669529663687f * 1.4426950408889634f); // 32^-0.5 * log2(e)
    Wt[(size_t)w * En * Hn + (size_t)n * En + kx] = f2bf(f);
}

// ---------------- K1: FUSED qkv projection, 2-phase pipelined ----------------
// BM=64, BN=384 (q|k|v), BK=32. 512 thr = 8 waves (2M x 4N), wave tile 32x96.
// Double-buffered LDS; loads for step t+1 issued BEFORE MFMA of step t;
// convert + ds_write after MFMA; ONE barrier per step.
__global__ __launch_bounds__(512, 4) void qkv_fused(const float* __restrict__ x,
                                                    const unsigned short* __restrict__ Wt,
                                                    unsigned short* __restrict__ qs,
                                                    unsigned short* __restrict__ ks,
                                                    unsigned short* __restrict__ vT) {
    __shared__ unsigned short Al[2][64][40];    // 80B row stride (16B-aligned, spread)
    __shared__ unsigned short Bl[2][384][40];
    const int m0 = blockIdx.x * 64;
    const int b = m0 >> 12;
    const int tb = m0 & (Tn - 1);
    const int t = threadIdx.x;
    const int lane = t & 63, wid = t >> 6;
    const int wm = wid >> 2, wn = wid & 3;
    const int fr = lane & 15, fq = lane >> 4;
    // staging assignment
    const int ar = t >> 3, ac = t & 7;   // A: 64 rows x 8 float4-chunks
    const int br = t >> 2, bc = t & 3;   // B: 128 rows per it x 4 16B-chunks

    f32x4 acc[2][6] = {};

    // prologue: stage step 0 into buf 0
    {
        float4 a0 = *reinterpret_cast<const float4*>(&x[(size_t)(m0 + ar) * En + ac * 4]);
        u32x4 b0[3];
        #pragma unroll
        for (int it = 0; it < 3; ++it)
            b0[it] = *reinterpret_cast<const u32x4*>(&Wt[(size_t)(it * 128 + br) * En + bc * 8]);
        ushort4 o;
        o.x = f2bf(a0.x); o.y = f2bf(a0.y); o.z = f2bf(a0.z); o.w = f2bf(a0.w);
        *reinterpret_cast<ushort4*>(&Al[0][ar][ac * 4]) = o;
        #pragma unroll
        for (int it = 0; it < 3; ++it)
            *reinterpret_cast<u32x4*>(&Bl[0][it * 128 + br][bc * 8]) = b0[it];
    }
    __syncthreads();

    int cur = 0;
    for (int step = 0; step < 64; ++step) {
        // phase 1: issue next-step global loads (latency hides under MFMA below)
        float4 an;
        u32x4 bn[3];
        if (step < 63) {
            const int kn = (step + 1) * 32;
            an = *reinterpret_cast<const float4*>(&x[(size_t)(m0 + ar) * En + kn + ac * 4]);
            #pragma unroll
            for (int it = 0; it < 3; ++it)
                bn[it] = *reinterpret_cast<const u32x4*>(&Wt[(size_t)(it * 128 + br) * En + kn + bc * 8]);
        }
        // phase 2: compute current buffer
        bf16x8 av[2], bv[6];
        #pragma unroll
        for (int mi = 0; mi < 2; ++mi)
            av[mi] = *reinterpret_cast<const bf16x8*>(&Al[cur][wm * 32 + mi * 16 + fr][fq * 8]);
        #pragma unroll
        for (int ni = 0; ni < 6; ++ni)
            bv[ni] = *reinterpret_cast<const bf16x8*>(&Bl[cur][wn * 96 + ni * 16 + fr][fq * 8]);
        #pragma unroll
        for (int mi = 0; mi < 2; ++mi)
            #pragma unroll
            for (int ni = 0; ni < 6; ++ni)
                acc[mi][ni] = __builtin_amdgcn_mfma_f32_16x16x32_bf16(av[mi], bv[ni], acc[mi][ni], 0, 0, 0);
        // phase 3: convert + write next tile into the other buffer
        if (step < 63) {
            ushort4 o;
            o.x = f2bf(an.x); o.y = f2bf(an.y); o.z = f2bf(an.z); o.w = f2bf(an.w);
            *reinterpret_cast<ushort4*>(&Al[cur ^ 1][ar][ac * 4]) = o;
            #pragma unroll
            for (int it = 0; it < 3; ++it)
                *reinterpret_cast<u32x4*>(&Bl[cur ^ 1][it * 128 + br][bc * 8]) = bn[it];
            __syncthreads();
        }
        cur ^= 1;
    }

    #pragma unroll
    for (int mi = 0; mi < 2; ++mi)
        #pragma unroll
        for (int ni = 0; ni < 6; ++ni) {
            int c = wn * 96 + ni * 16 + fr;   // 0..383: [q | k | v]
            int w = c >> 7, h = c & 127;
            #pragma unroll
            for (int r = 0; r < 4; ++r) {
                int rloc = wm * 32 + mi * 16 + fq * 4 + r;
                unsigned short val = f2bf(acc[mi][ni][r]);
                if (w == 0)      qs[(size_t)(m0 + rloc) * Hn + h] = val;
                else if (w == 1) ks[(size_t)(m0 + rloc) * Hn + h] = val;
                else             vT[((size_t)b * Hn + h) * Tn + tb + rloc] = val;
            }
        }
}

// ---------------- K2: S' = q'.k^T -> fp16 [b][q][k]  +  fused column stats ---
// softmax is over axis=1 (query): per-column (key) max/sumexp partial per tile
__global__ __launch_bounds__(256) void s_gemm(const unsigned short* __restrict__ qs,
                                              const unsigned short* __restrict__ ks,
                                              __half* __restrict__ S,
                                              float2* __restrict__ part) {
    __shared__ unsigned short Ql[128][88];
    __shared__ unsigned short Kl[128][88];
    __shared__ float2 sPart[4][128];
    const int bid = blockIdx.x;
    const int b = bid >> 10;
    const int rem = bid & 1023;
    const int mt = rem >> 5;            // q tile index (0..31)
    const int m0 = mt << 7;
    const int n0 = (rem & 31) << 7;     // key tile (fastest -> k panel L2 reuse)
    const unsigned short* qb = qs + (size_t)b * Tn * Hn;
    const unsigned short* kb = ks + (size_t)b * Tn * Hn;
    const int t = threadIdx.x;
    const int lane = t & 63, wid = t >> 6;
    const int wr = (wid >> 1) * 64, wc = (wid & 1) * 64;
    const int fr = lane & 15, fq = lane >> 4;
    f32x4 acc[4][4] = {};
    #pragma unroll
    for (int kh = 0; kh < 2; ++kh) {
        __syncthreads();
        #pragma unroll
        for (int it = 0; it < 4; ++it) {
            int idx = it * 256 + t;
            int row = idx >> 3, ch = idx & 7;
            *reinterpret_cast<u32x4*>(&Ql[row][ch * 8]) =
                *reinterpret_cast<const u32x4*>(&qb[(size_t)(m0 + row) * Hn + kh * 64 + ch * 8]);
            *reinterpret_cast<u32x4*>(&Kl[row][ch * 8]) =
                *reinterpret_cast<const u32x4*>(&kb[(size_t)(n0 + row) * Hn + kh * 64 + ch * 8]);
        }
        __syncthreads();
        #pragma unroll
        for (int ksub = 0; ksub < 2; ++ksub) {
            bf16x8 av[4], bv[4];
            #pragma unroll
            for (int mi = 0; mi < 4; ++mi)
                av[mi] = *reinterpret_cast<const bf16x8*>(&Ql[wr + mi * 16 + fr][ksub * 32 + fq * 8]);
            #pragma unroll
            for (int ni = 0; ni < 4; ++ni)
                bv[ni] = *reinterpret_cast<const bf16x8*>(&Kl[wc + ni * 16 + fr][ksub * 32 + fq * 8]);
            #pragma unroll
            for (int mi = 0; mi < 4; ++mi)
                #pragma unroll
                for (int ni = 0; ni < 4; ++ni)
                    acc[mi][ni] = __builtin_amdgcn_mfma_f32_16x16x32_bf16(av[mi], bv[ni], acc[mi][ni], 0, 0, 0);
        }
    }
    // write S tile
    __half* Sb = S + (size_t)b * Tn * Tn;
    #pragma unroll
    for (int mi = 0; mi < 4; ++mi)
        #pragma unroll
        for (int ni = 0; ni < 4; ++ni)
            #pragma unroll
            for (int r = 0; r < 4; ++r) {
                int row = m0 + wr + mi * 16 + fq * 4 + r;
                int col = n0 + wc + ni * 16 + fr;
                Sb[(size_t)row * Tn + col] = __float2half(acc[mi][ni][r]);
            }
    // fused per-column (over q) stats: in-lane 16 vals -> shfl over fq -> LDS over waves
    #pragma unroll
    for (int ni = 0; ni < 4; ++ni) {
        float mm = -INFINITY;
        #pragma unroll
        for (int mi = 0; mi < 4; ++mi)
            #pragma unroll
            for (int r = 0; r < 4; ++r)
                mm = fmaxf(mm, acc[mi][ni][r]);
        float ll = 0.f;
        #pragma unroll
        for (int mi = 0; mi < 4; ++mi)
            #pragma unroll
            for (int r = 0; r < 4; ++r)
                ll += __builtin_amdgcn_exp2f(acc[mi][ni][r] - mm);
        #pragma unroll
        for (int off = 16; off <= 32; off <<= 1) {
            float mo = __shfl_xor(mm, off);
            float lo = __shfl_xor(ll, off);
            float mn = fmaxf(mm, mo);
            ll = ll * __builtin_amdgcn_exp2f(mm - mn) + lo * __builtin_amdgcn_exp2f(mo - mn);
            mm = mn;
        }
        if (fq == 0) sPart[wid][wc + ni * 16 + fr] = make_float2(mm, ll);
    }
    __syncthreads();
    if (t < 128) {
        int col = t;
        int w = col >> 6;                      // waves (0,2) own cols 0-63; (1,3) own 64-127
        float2 a = sPart[w][col];
        float2 c2 = sPart[w + 2][col];
        float mn = fmaxf(a.x, c2.x);
        float L = a.y * __builtin_amdgcn_exp2f(a.x - mn) + c2.y * __builtin_amdgcn_exp2f(c2.x - mn);
        part[((size_t)b * Tn + n0 + col) * 32 + mt] = make_float2(mn, L);
    }
}

// ---------------- K3: combine 32 tile-partials -> stats[b][k] = (m, 1/l) -----
__global__ __launch_bounds__(256) void stats_comb(const float2* __restrict__ part,
                                                  float2* __restrict__ stats) {
    int g = blockIdx.x * 256 + threadIdx.x;   // 8*4096
    const float2* pp = part + (size_t)g * 32;
    float M = -INFINITY;
    #pragma unroll
    for (int i = 0; i < 32; ++i) M = fmaxf(M, pp[i].x);
    float L = 0.f;
    #pragma unroll
    for (int i = 0; i < 32; ++i) L += pp[i].y * __builtin_amdgcn_exp2f(pp[i].x - M);
    stats[g] = make_float2(M, 1.0f / L);
}

// ---------------- K4: out[b][q][h] = sum_k exp2(S'-m_k)*r_k * v[k][h] --------
// grid: 8 * (4096/64); BM=64, BN=128, BK=64
__global__ __launch_bounds__(256) void pv_gemm(const __half* __restrict__ S,
                                               const float2* __restrict__ stats,
                                               const unsigned short* __restrict__ vT,
                                               float* __restrict__ out) {
    __shared__ unsigned short Pl[64][88];
    __shared__ unsigned short Vl[128][88];
    const int bid = blockIdx.x;
    const int b = bid >> 6;
    const int q0 = (bid & 63) * 64;
    const int t = threadIdx.x;
    const int lane = t & 63, wid = t >> 6;
    const int wr = (wid & 1) * 32, wc = (wid >> 1) * 64;
    const int fr = lane & 15, fq = lane >> 4;
    const __half* Sb = S + (size_t)b * Tn * Tn;
    const unsigned short* Vb = vT + (size_t)b * Hn * Tn;
    const float2* stb = stats + b * Tn;
    const int prow = t >> 3;   // 0..31
    const int pch = t & 7;     // fixed 16B chunk within 64-col panel
    f32x4 acc[2][4] = {};
    for (int kt = 0; kt < 64; ++kt) {
        __syncthreads();
        // stats for my 8 columns (L2 resident: 32KB per batch)
        const float4* stq = reinterpret_cast<const float4*>(stb + kt * 64 + pch * 8);
        float4 s0 = stq[0], s1 = stq[1], s2 = stq[2], s3 = stq[3];
        float m2[8] = {s0.x, s0.z, s1.x, s1.z, s2.x, s2.z, s3.x, s3.z};
        float rr[8] = {s0.y, s0.w, s1.y, s1.w, s2.y, s2.w, s3.y, s3.w};
        // P tile: fp16 S' -> exp2(s - m)*r -> bf16
        #pragma unroll
        for (int it = 0; it < 2; ++it) {
            int row = it * 32 + prow;
            u32x4 raw = *reinterpret_cast<const u32x4*>(&Sb[(size_t)(q0 + row) * Tn + kt * 64 + pch * 8]);
            unsigned pk[4];
            #pragma unroll
            for (int i = 0; i < 4; ++i) {
                float f0 = h2f((unsigned short)(raw[i] & 0xffff));
                float f1 = h2f((unsigned short)(raw[i] >> 16));
                float p0 = __builtin_amdgcn_exp2f(f0 - m2[2 * i]) * rr[2 * i];
                float p1 = __builtin_amdgcn_exp2f(f1 - m2[2 * i + 1]) * rr[2 * i + 1];
                pk[i] = (unsigned)f2bf(p0) | ((unsigned)f2bf(p1) << 16);
            }
            *reinterpret_cast<u32x4*>(&Pl[row][pch * 8]) = *reinterpret_cast<u32x4*>(pk);
        }
        // V tile (vT is [h][t]: linear rows)
        #pragma unroll
        for (int it = 0; it < 4; ++it) {
            int row = it * 32 + prow;
            *reinterpret_cast<u32x4*>(&Vl[row][pch * 8]) =
                *reinterpret_cast<const u32x4*>(&Vb[(size_t)row * Tn + kt * 64 + pch * 8]);
        }
        __syncthreads();
        #pragma unroll
        for (int ksub = 0; ksub < 2; ++ksub) {
            bf16x8 av[2], bv[4];
            #pragma unroll
            for (int mi = 0; mi < 2; ++mi)
                av[mi] = *reinterpret_cast<const bf16x8*>(&Pl[wr + mi * 16 + fr][ksub * 32 + fq * 8]);
            #pragma unroll
            for (int ni = 0; ni < 4; ++ni)
                bv[ni] = *reinterpret_cast<const bf16x8*>(&Vl[wc + ni * 16 + fr][ksub * 32 + fq * 8]);
            #pragma unroll
            for (int mi = 0; mi < 2; ++mi)
                #pragma unroll
                for (int ni = 0; ni < 4; ++ni)
                    acc[mi][ni] = __builtin_amdgcn_mfma_f32_16x16x32_bf16(av[mi], bv[ni], acc[mi][ni], 0, 0, 0);
        }
    }
    #pragma unroll
    for (int mi = 0; mi < 2; ++mi)
        #pragma unroll
        for (int ni = 0; ni < 4; ++ni)
            #pragma unroll
            for (int r = 0; r < 4; ++r) {
                int row = q0 + wr + mi * 16 + fq * 4 + r;
                int col = wc + ni * 16 + fr;
                out[((size_t)b * Tn + row) * Hn + col] = acc[mi][ni][r];
            }
}

extern "C" void kernel_launch(void* const* d_in, const int* in_sizes, int n_in,
                              void* d_out, int out_size, void* d_ws, size_t ws_size,
                              hipStream_t stream) {
    const float* x  = (const float*)d_in[0];
    const float* Wq = (const float*)d_in[1];
    const float* Wk = (const float*)d_in[2];
    const float* Wv = (const float*)d_in[3];
    float* out = (float*)d_out;

    char* p = (char*)d_ws;
    unsigned short* qs = (unsigned short*)p; p += (size_t)Bn * Tn * Hn * 2;
    unsigned short* ks = (unsigned short*)p; p += (size_t)Bn * Tn * Hn * 2;
    unsigned short* vT = (unsigned short*)p; p += (size_t)Bn * Tn * Hn * 2;
    unsigned short* Wt = (unsigned short*)p; p += (size_t)3 * En * Hn * 2;
    __half* S          = (__half*)p;         p += (size_t)Bn * Tn * Tn * 2;
    float2* part       = (float2*)p;         p += (size_t)Bn * Tn * 32 * sizeof(float2);
    float2* stats      = (float2*)p;         p += (size_t)Bn * Tn * sizeof(float2);
    size_t needed = (size_t)(p - (char*)d_ws);
    if (ws_size < needed) return;  // workspace too small: leave output poisoned as a clear signal

    prep_w<<<dim3(3 * En * Hn / 256), dim3(256), 0, stream>>>(Wq, Wk, Wv, Wt);
    qkv_fused<<<dim3(Bn * Tn / 64), dim3(512), 0, stream>>>(x, Wt, qs, ks, vT);
    s_gemm<<<dim3(Bn * (Tn / 128) * (Tn / 128)), dim3(256), 0, stream>>>(qs, ks, S, part);
    stats_comb<<<dim3(Bn * Tn / 256), dim3(256), 0, stream>>>(part, stats);
    pv_gemm<<<dim3(Bn * (Tn / 64)), dim3(256), 0, stream>>>(S, stats, vT, out);
}